// Round 3
// baseline (291.546 us; speedup 1.0000x reference)
//
#include <hip/hip_runtime.h>

// AttentionBlock: B=8, T=2048, D=K=V=512. Inputs fp32, OUTPUT fp32.
// out = x + einsum('bts,bsv->btv', softmax_over_t(mask(q@k^T))/sqrt(512), v)
// NOTE: softmax is over axis=1 (query axis t) per key-column s — column softmax.

typedef __attribute__((ext_vector_type(4))) float f32x4;
typedef __attribute__((ext_vector_type(8))) short s16x8;
typedef __attribute__((ext_vector_type(4))) short s16x4;

#define SENT   -1e30f
#define SQRTK  22.627416997969522f   // sqrt(512)

__device__ __forceinline__ short f2bf(float f) {
    union { float f; unsigned int i; } c; c.f = f;
    unsigned int x = c.i;
    return (short)((x + 0x7fffu + ((x >> 16) & 1u)) >> 16);
}

// ---------------------------------------------------------------------------
// fp32 -> bf16 cast, 4 elems/thread, vectorized.
// ---------------------------------------------------------------------------
__global__ __launch_bounds__(256) void k_cast(
    const float* __restrict__ in, unsigned short* __restrict__ out, int n4)
{
    int i = blockIdx.x * 256 + threadIdx.x;
    if (i >= n4) return;
    f32x4 v = *(const f32x4*)(in + (size_t)i * 4);
    s16x4 o;
#pragma unroll
    for (int j = 0; j < 4; ++j) o[j] = f2bf(v[j]);
    *(s16x4*)(out + (size_t)i * 4) = o;
}

// ---------------------------------------------------------------------------
// Generic bf16 GEMM: C[M][N] = A[M][512] . Bt[N][512]^T + bias(fp32), bf16 out.
// 128x128 tile, BK=32, 4 waves (2x2), each wave 64x64 via 4x4 16x16x32 MFMAs.
// ---------------------------------------------------------------------------
__global__ __launch_bounds__(256) void k_proj(
    const unsigned short* __restrict__ A,    // [M][512] bf16
    const unsigned short* __restrict__ Bt,   // [N][512] bf16
    const float* __restrict__ bias,          // [M] if per_row else [N], fp32
    unsigned short* __restrict__ C,          // [M][N] bf16
    int N, int bias_per_row)
{
    __shared__ short la[128][32];
    __shared__ short lb[128][32];
    const int tid  = threadIdx.x;
    const int wave = tid >> 6, lane = tid & 63;
    const int wr = (wave >> 1) * 64, wc = (wave & 1) * 64;
    const int m0 = blockIdx.x * 128, n0 = blockIdx.y * 128;
    const int srow = tid >> 2, scol = (tid & 3) * 8;
    const int frl = lane & 15, kb = (lane >> 4) * 8, rg4 = (lane >> 4) * 4;
    f32x4 acc[4][4] = {};
    for (int k0 = 0; k0 < 512; k0 += 32) {
#pragma unroll
        for (int p = 0; p < 2; ++p) {
            int r = srow + p * 64;
            *(s16x8*)(&la[r][scol]) = *(const s16x8*)(A  + (size_t)(m0 + r) * 512 + k0 + scol);
            *(s16x8*)(&lb[r][scol]) = *(const s16x8*)(Bt + (size_t)(n0 + r) * 512 + k0 + scol);
        }
        __syncthreads();
        s16x8 af[4], bfr[4];
#pragma unroll
        for (int i = 0; i < 4; ++i) af[i]  = *(const s16x8*)(&la[wr + i * 16 + frl][kb]);
#pragma unroll
        for (int i = 0; i < 4; ++i) bfr[i] = *(const s16x8*)(&lb[wc + i * 16 + frl][kb]);
#pragma unroll
        for (int mi = 0; mi < 4; ++mi)
#pragma unroll
            for (int ni = 0; ni < 4; ++ni)
                acc[mi][ni] = __builtin_amdgcn_mfma_f32_16x16x32_bf16(af[mi], bfr[ni], acc[mi][ni], 0, 0, 0);
        __syncthreads();
    }
#pragma unroll
    for (int mi = 0; mi < 4; ++mi)
#pragma unroll
        for (int ni = 0; ni < 4; ++ni) {
            int col = n0 + wc + ni * 16 + frl;
#pragma unroll
            for (int r = 0; r < 4; ++r) {
                int row = m0 + wr + mi * 16 + rg4 + r;
                float bv = bias[bias_per_row ? row : col];
                C[(size_t)row * N + col] = f2bf(acc[mi][ni][r] + bv);
            }
        }
}

// ---------------------------------------------------------------------------
// L[b][t][s] = Q[b,t,:] . K[b,s,:]  (fp32), masked (s>t) -> SENT.
// Fully-masked tiles (s0 > t0+127) skipped entirely (never read downstream).
// ---------------------------------------------------------------------------
__global__ __launch_bounds__(256) void k_logits(
    const unsigned short* __restrict__ Q,   // [B][2048][512]
    const unsigned short* __restrict__ Km,  // [B][2048][512]
    float* __restrict__ L)                  // [B][2048][2048]
{
    const int b  = blockIdx.z;
    const int t0 = blockIdx.x * 128, s0 = blockIdx.y * 128;
    if (s0 > t0 + 127) return;  // fully masked tile
    const unsigned short* A  = Q  + (size_t)b * 2048 * 512;
    const unsigned short* Bt = Km + (size_t)b * 2048 * 512;
    float* Lb = L + (size_t)b * 2048 * 2048;

    __shared__ short la[128][32];
    __shared__ short lb[128][32];
    const int tid  = threadIdx.x;
    const int wave = tid >> 6, lane = tid & 63;
    const int wr = (wave >> 1) * 64, wc = (wave & 1) * 64;
    const int srow = tid >> 2, scol = (tid & 3) * 8;
    const int frl = lane & 15, kb = (lane >> 4) * 8, rg4 = (lane >> 4) * 4;
    f32x4 acc[4][4] = {};
    for (int k0 = 0; k0 < 512; k0 += 32) {
#pragma unroll
        for (int p = 0; p < 2; ++p) {
            int r = srow + p * 64;
            *(s16x8*)(&la[r][scol]) = *(const s16x8*)(A  + (size_t)(t0 + r) * 512 + k0 + scol);
            *(s16x8*)(&lb[r][scol]) = *(const s16x8*)(Bt + (size_t)(s0 + r) * 512 + k0 + scol);
        }
        __syncthreads();
        s16x8 af[4], bfr[4];
#pragma unroll
        for (int i = 0; i < 4; ++i) af[i]  = *(const s16x8*)(&la[wr + i * 16 + frl][kb]);
#pragma unroll
        for (int i = 0; i < 4; ++i) bfr[i] = *(const s16x8*)(&lb[wc + i * 16 + frl][kb]);
#pragma unroll
        for (int mi = 0; mi < 4; ++mi)
#pragma unroll
            for (int ni = 0; ni < 4; ++ni)
                acc[mi][ni] = __builtin_amdgcn_mfma_f32_16x16x32_bf16(af[mi], bfr[ni], acc[mi][ni], 0, 0, 0);
        __syncthreads();
    }
#pragma unroll
    for (int mi = 0; mi < 4; ++mi)
#pragma unroll
        for (int ni = 0; ni < 4; ++ni) {
            int col = s0 + wc + ni * 16 + frl;
#pragma unroll
            for (int r = 0; r < 4; ++r) {
                int row = t0 + wr + mi * 16 + rg4 + r;
                Lb[(size_t)row * 2048 + col] = (col <= row) ? acc[mi][ni][r] : SENT;
            }
        }
}

// ---------------------------------------------------------------------------
// Column-softmax stats. Pass 1: online (m, Z) per (column s, t-chunk).
// Only reads t >= s&~127 (everything below is in skipped/unwritten tiles).
// ---------------------------------------------------------------------------
__global__ __launch_bounds__(256) void k_stats1(
    const float* __restrict__ L, float* __restrict__ pm, float* __restrict__ pz)
{
    const int sc = blockIdx.x, tc = blockIdx.y, b = blockIdx.z;
    const int s = sc * 256 + threadIdx.x;
    const float* Lb = L + (size_t)b * 2048 * 2048;
    const int tstart = s & ~127;
    int t0 = tc * 256; if (t0 < tstart) t0 = tstart;
    const int t1 = tc * 256 + 256;
    float m = SENT, z = 0.f;
    for (int t = t0; t < t1; ++t) {
        float x = Lb[(size_t)t * 2048 + s];
        float nm = fmaxf(m, x);
        z = z * __expf(m - nm) + __expf(x - nm);
        m = nm;
    }
    const int o = (b * 8 + tc) * 2048 + s;
    pm[o] = m; pz[o] = z;
}

// Pass 2: combine 8 chunk partials -> column max + rcp = 1/(Z*sqrt(512)).
__global__ __launch_bounds__(256) void k_stats2(
    const float* __restrict__ pm, const float* __restrict__ pz,
    float* __restrict__ mcol, float* __restrict__ rcp)
{
    const int i = blockIdx.x * 256 + threadIdx.x;  // b*2048 + s
    const int b = i >> 11, s = i & 2047;
    float M = SENT;
#pragma unroll
    for (int tc = 0; tc < 8; ++tc) M = fmaxf(M, pm[(b * 8 + tc) * 2048 + s]);
    float Z = 0.f;
#pragma unroll
    for (int tc = 0; tc < 8; ++tc) {
        int o = (b * 8 + tc) * 2048 + s;
        Z += pz[o] * __expf(pm[o] - M);
    }
    mcol[i] = M;
    rcp[i]  = 1.0f / (Z * SQRTK);
}

// ---------------------------------------------------------------------------
// out[b,t,v] = x[b,t,v] + sum_s exp(L[t,s]-m_s)*rcp_s * Vt[v, b*2048+s]
// A-tile staged with fused exp (fp32->bf16), B-tile from transposed V.
// Output written as FP32 (reference output dtype).
// ---------------------------------------------------------------------------
__global__ __launch_bounds__(256) void k_out(
    const float* __restrict__ L,           // [B][2048][2048]
    const float* __restrict__ mcol,        // [B*2048]
    const float* __restrict__ rcp,         // [B*2048]
    const unsigned short* __restrict__ Vt, // [512][B*2048] bf16
    const float* __restrict__ X,           // [B][2048][512] fp32
    float* __restrict__ Y)                 // [B][2048][512] fp32
{
    __shared__ short la[128][32];   // P'[t][s]
    __shared__ short lb[128][32];   // Vt[v][s]
    const int b  = blockIdx.z;
    const int t0 = blockIdx.x * 128, v0 = blockIdx.y * 128;
    const float* Lb = L + (size_t)b * 2048 * 2048;
    const float* mb = mcol + b * 2048;
    const float* rb = rcp  + b * 2048;
    const int tid  = threadIdx.x;
    const int wave = tid >> 6, lane = tid & 63;
    const int wr = (wave >> 1) * 64, wc = (wave & 1) * 64;
    const int frl = lane & 15, kb = (lane >> 4) * 8, rg4 = (lane >> 4) * 4;
    f32x4 acc[4][4] = {};
    const int smax = (t0 + 128 < 2048) ? t0 + 128 : 2048;  // causal: s <= t only
    for (int s0 = 0; s0 < smax; s0 += 32) {
        // stage A: 128(t) x 32(s) of P' = exp(L - m_s) * rcp_s, bf16
#pragma unroll
        for (int p = 0; p < 4; ++p) {
            int idx = tid + p * 256;       // 0..1023
            int tr  = idx >> 3;            // 0..127
            int sc  = (idx & 7) * 4;       // 0..28
            f32x4 l4 = *(const f32x4*)(Lb + (size_t)(t0 + tr) * 2048 + s0 + sc);
            f32x4 m4 = *(const f32x4*)(mb + s0 + sc);
            f32x4 r4 = *(const f32x4*)(rb + s0 + sc);
            s16x4 o;
#pragma unroll
            for (int j = 0; j < 4; ++j)
                o[j] = f2bf(__expf(l4[j] - m4[j]) * r4[j]);
            *(s16x4*)(&la[tr][sc]) = o;
        }
        // stage B: Vt rows v0..v0+127, cols b*2048 + s0 .. +31
#pragma unroll
        for (int p = 0; p < 2; ++p) {
            int idx = tid + p * 256;       // 0..511
            int vr  = idx >> 2;            // 0..127
            int scB = (idx & 3) * 8;
            *(s16x8*)(&lb[vr][scB]) =
                *(const s16x8*)(Vt + (size_t)(v0 + vr) * 16384 + b * 2048 + s0 + scB);
        }
        __syncthreads();
        s16x8 af[4], bfr[4];
#pragma unroll
        for (int i = 0; i < 4; ++i) af[i]  = *(const s16x8*)(&la[wr + i * 16 + frl][kb]);
#pragma unroll
        for (int i = 0; i < 4; ++i) bfr[i] = *(const s16x8*)(&lb[wc + i * 16 + frl][kb]);
#pragma unroll
        for (int mi = 0; mi < 4; ++mi)
#pragma unroll
            for (int ni = 0; ni < 4; ++ni)
                acc[mi][ni] = __builtin_amdgcn_mfma_f32_16x16x32_bf16(af[mi], bfr[ni], acc[mi][ni], 0, 0, 0);
        __syncthreads();
    }
#pragma unroll
    for (int mi = 0; mi < 4; ++mi)
#pragma unroll
        for (int ni = 0; ni < 4; ++ni) {
            int col = v0 + wc + ni * 16 + frl;
#pragma unroll
            for (int r = 0; r < 4; ++r) {
                int row = t0 + wr + mi * 16 + rg4 + r;
                size_t o = ((size_t)b * 2048 + row) * 512 + col;
                Y[o] = acc[mi][ni][r] + X[o];
            }
        }
}

extern "C" void kernel_launch(void* const* d_in, const int* in_sizes, int n_in,
                              void* d_out, int out_size, void* d_ws, size_t ws_size,
                              hipStream_t stream) {
    const float* Xf  = (const float*)d_in[0];
    const float* Wkf = (const float*)d_in[1];
    const float* bkf = (const float*)d_in[2];
    const float* Wqf = (const float*)d_in[3];
    const float* bqf = (const float*)d_in[4];
    const float* Wvf = (const float*)d_in[5];
    const float* bvf = (const float*)d_in[6];
    float* Y = (float*)d_out;
    char* ws = (char*)d_ws;

    // workspace layout (bytes); total ~195 MB
    unsigned short* Xb  = (unsigned short*)(ws);                    // 16 MB  [16384][512]
    unsigned short* Qb  = (unsigned short*)(ws + 16777216);         // 16 MB  [16384][512]
    unsigned short* Kb  = (unsigned short*)(ws + 33554432);         // 16 MB  [16384][512]
    unsigned short* Vt  = (unsigned short*)(ws + 50331648);         // 16 MB  [512][16384]
    unsigned short* Wkb = (unsigned short*)(ws + 67108864);         // 512 KB [512][512]
    unsigned short* Wqb = (unsigned short*)(ws + 67633152);         // 512 KB
    unsigned short* Wvb = (unsigned short*)(ws + 68157440);         // 512 KB
    float*          Lg  = (float*)(ws + 68681728);                  // 128 MB [8][2048][2048]
    float*          pm  = (float*)(ws + 202899456);                 // 512 KB
    float*          pz  = (float*)(ws + 203423744);                 // 512 KB
    float*          mc  = (float*)(ws + 203948032);                 // 64 KB
    float*          rc  = (float*)(ws + 204013568);                 // 64 KB

    dim3 blk(256);
    // fp32 -> bf16 casts
    k_cast<<<dim3(8192), blk, 0, stream>>>(Xf,  Xb,  2097152);  // 8M elems
    k_cast<<<dim3(256),  blk, 0, stream>>>(Wkf, Wkb, 65536);    // 256K elems
    k_cast<<<dim3(256),  blk, 0, stream>>>(Wqf, Wqb, 65536);
    k_cast<<<dim3(256),  blk, 0, stream>>>(Wvf, Wvb, 65536);
    // Q = X.Wq^T + bq ; K = X.Wk^T + bk  (M=16384, N=512)
    k_proj<<<dim3(128, 4), blk, 0, stream>>>(Xb, Wqb, bqf, Qb, 512, 0);
    k_proj<<<dim3(128, 4), blk, 0, stream>>>(Xb, Wkb, bkf, Kb, 512, 0);
    // Vt = Wv.X^T + bv (per-row bias) -> values transposed [512][16384]
    k_proj<<<dim3(4, 128), blk, 0, stream>>>(Wvb, Xb, bvf, Vt, 16384, 1);
    // logits (t-major), causal mask, fp32
    k_logits<<<dim3(16, 16, 8), blk, 0, stream>>>(Qb, Kb, Lg);
    // column softmax stats
    k_stats1<<<dim3(8, 8, 8), blk, 0, stream>>>(Lg, pm, pz);
    k_stats2<<<dim3(64), blk, 0, stream>>>(pm, pz, mc, rc);
    // P.V + residual
    k_out<<<dim3(16, 4, 8), blk, 0, stream>>>(Lg, mc, rc, Vt, Xf, Y);
}

// Round 4
// 174.722 us; speedup vs baseline: 1.6686x; 1.6686x over previous
//
#include <hip/hip_runtime.h>

// AttentionBlock: B=8, T=2048, D=K=V=512. Inputs fp32, OUTPUT fp32.
// out = x + einsum('bts,bsv->btv', softmax_over_t(mask(q@k^T))/sqrt(512), v)
// softmax is over axis=1 (query axis t) per key-column s — column softmax.

typedef __attribute__((ext_vector_type(4))) float f32x4;
typedef __attribute__((ext_vector_type(8))) short s16x8;
typedef __attribute__((ext_vector_type(4))) short s16x4;

#define SENT   -1e30f
#define SQRTK  22.627416997969522f   // sqrt(512)

__device__ __forceinline__ short f2bf(float f) {
    union { float f; unsigned int i; } c; c.f = f;
    unsigned int x = c.i;
    return (short)((x + 0x7fffu + ((x >> 16) & 1u)) >> 16);
}

// ---------------------------------------------------------------------------
// fp32 -> bf16 cast, 4 elems/thread, vectorized.
// ---------------------------------------------------------------------------
__global__ __launch_bounds__(256) void k_cast(
    const float* __restrict__ in, unsigned short* __restrict__ out, int n4)
{
    int i = blockIdx.x * 256 + threadIdx.x;
    if (i >= n4) return;
    f32x4 v = *(const f32x4*)(in + (size_t)i * 4);
    s16x4 o;
#pragma unroll
    for (int j = 0; j < 4; ++j) o[j] = f2bf(v[j]);
    *(s16x4*)(out + (size_t)i * 4) = o;
}

// Merged cast of the three 512x512 weights (one launch instead of three).
__global__ __launch_bounds__(256) void k_castw(
    const float* __restrict__ a, const float* __restrict__ b, const float* __restrict__ c,
    unsigned short* __restrict__ oa, unsigned short* __restrict__ ob, unsigned short* __restrict__ oc)
{
    int i = blockIdx.x * 256 + threadIdx.x;   // 0..196607 float4-groups
    const float* src; unsigned short* dst; int j;
    if (i < 65536)       { src = a; dst = oa; j = i; }
    else if (i < 131072) { src = b; dst = ob; j = i - 65536; }
    else                 { src = c; dst = oc; j = i - 131072; }
    f32x4 v = *(const f32x4*)(src + (size_t)j * 4);
    s16x4 o;
#pragma unroll
    for (int jj = 0; jj < 4; ++jj) o[jj] = f2bf(v[jj]);
    *(s16x4*)(dst + (size_t)j * 4) = o;
}

// ---------------------------------------------------------------------------
// Generic bf16 GEMM: C[M][N] = A[M][512] . Bt[N][512]^T + bias(fp32), bf16 out.
// 128x128 tile, BK=32, 4 waves (2x2), double-buffered LDS, reg-staged loads.
// ---------------------------------------------------------------------------
__global__ __launch_bounds__(256) void k_proj(
    const unsigned short* __restrict__ A,    // [M][512] bf16
    const unsigned short* __restrict__ Bt,   // [N][512] bf16
    const float* __restrict__ bias,          // [M] if per_row else [N], fp32
    unsigned short* __restrict__ C,          // [M][N] bf16
    int N, int bias_per_row)
{
    __shared__ short la[2][128][32];
    __shared__ short lb[2][128][32];
    const int tid  = threadIdx.x;
    const int wave = tid >> 6, lane = tid & 63;
    const int wr = (wave >> 1) * 64, wc = (wave & 1) * 64;
    const int m0 = blockIdx.x * 128, n0 = blockIdx.y * 128;
    const int srow = tid >> 2, scol = (tid & 3) * 8;
    const int frl = lane & 15, kb = (lane >> 4) * 8, rg4 = (lane >> 4) * 4;
    f32x4 acc[4][4] = {};
    s16x8 ra[2], rb[2];

#define PROJ_LOAD(K0) \
    { _Pragma("unroll") for (int p = 0; p < 2; ++p) { \
        int r = srow + p * 64; \
        ra[p] = *(const s16x8*)(A  + (size_t)(m0 + r) * 512 + (K0) + scol); \
        rb[p] = *(const s16x8*)(Bt + (size_t)(n0 + r) * 512 + (K0) + scol); } }
#define PROJ_WRITE(BUF) \
    { _Pragma("unroll") for (int p = 0; p < 2; ++p) { \
        int r = srow + p * 64; \
        *(s16x8*)(&la[BUF][r][scol]) = ra[p]; \
        *(s16x8*)(&lb[BUF][r][scol]) = rb[p]; } }

    PROJ_LOAD(0);
    PROJ_WRITE(0);
    __syncthreads();
    for (int ks = 0; ks < 16; ++ks) {
        const int cur = ks & 1;
        if (ks < 15) PROJ_LOAD((ks + 1) * 32);
        s16x8 af[4], bfr[4];
#pragma unroll
        for (int i = 0; i < 4; ++i) af[i]  = *(const s16x8*)(&la[cur][wr + i * 16 + frl][kb]);
#pragma unroll
        for (int i = 0; i < 4; ++i) bfr[i] = *(const s16x8*)(&lb[cur][wc + i * 16 + frl][kb]);
#pragma unroll
        for (int mi = 0; mi < 4; ++mi)
#pragma unroll
            for (int ni = 0; ni < 4; ++ni)
                acc[mi][ni] = __builtin_amdgcn_mfma_f32_16x16x32_bf16(af[mi], bfr[ni], acc[mi][ni], 0, 0, 0);
        if (ks < 15) PROJ_WRITE(cur ^ 1);
        __syncthreads();
    }
#pragma unroll
    for (int mi = 0; mi < 4; ++mi)
#pragma unroll
        for (int ni = 0; ni < 4; ++ni) {
            int col = n0 + wc + ni * 16 + frl;
#pragma unroll
            for (int r = 0; r < 4; ++r) {
                int row = m0 + wr + mi * 16 + rg4 + r;
                float bv = bias[bias_per_row ? row : col];
                C[(size_t)row * N + col] = f2bf(acc[mi][ni][r] + bv);
            }
        }
#undef PROJ_LOAD
#undef PROJ_WRITE
}

// ---------------------------------------------------------------------------
// L[b][t][s] = Q[b,t,:].K[b,s,:] (fp32), masked (s>t) -> SENT, PLUS fused
// per-column (m, Z) partials per 128-row chunk. 1-D grid over the 136 valid
// triangular tiles x 8 batches (uniform work). Double-buffered.
// ---------------------------------------------------------------------------
__global__ __launch_bounds__(256) void k_logits(
    const unsigned short* __restrict__ Q,   // [B][2048][512]
    const unsigned short* __restrict__ Km,  // [B][2048][512]
    float* __restrict__ L,                  // [B][2048][2048]
    float* __restrict__ pm, float* __restrict__ pz)  // [B*16][2048]
{
    const int n = blockIdx.x;
    const int b = n & 7;
    const int p = n >> 3;                       // 0..135 triangular index
    int tt = (int)((sqrtf(8.f * p + 1.f) - 1.f) * 0.5f);
    while ((tt + 1) * (tt + 2) / 2 <= p) ++tt;
    while (tt * (tt + 1) / 2 > p) --tt;
    const int st = p - tt * (tt + 1) / 2;       // st <= tt
    const int t0 = tt * 128, s0 = st * 128;

    const unsigned short* A  = Q  + (size_t)b * 2048 * 512;
    const unsigned short* Bt = Km + (size_t)b * 2048 * 512;
    float* Lb = L + (size_t)b * 2048 * 2048;

    __shared__ short la[2][128][32];
    __shared__ short lb[2][128][32];
    __shared__ float sm[2][128];
    __shared__ float sz[2][128];
    const int tid  = threadIdx.x;
    const int wave = tid >> 6, lane = tid & 63;
    const int wr = (wave >> 1) * 64, wc = (wave & 1) * 64;
    const int srow = tid >> 2, scol = (tid & 3) * 8;
    const int frl = lane & 15, kb = (lane >> 4) * 8, rg4 = (lane >> 4) * 4;
    f32x4 acc[4][4] = {};
    s16x8 ra[2], rb[2];

#define LG_LOAD(K0) \
    { _Pragma("unroll") for (int q = 0; q < 2; ++q) { \
        int r = srow + q * 64; \
        ra[q] = *(const s16x8*)(A  + (size_t)(t0 + r) * 512 + (K0) + scol); \
        rb[q] = *(const s16x8*)(Bt + (size_t)(s0 + r) * 512 + (K0) + scol); } }
#define LG_WRITE(BUF) \
    { _Pragma("unroll") for (int q = 0; q < 2; ++q) { \
        int r = srow + q * 64; \
        *(s16x8*)(&la[BUF][r][scol]) = ra[q]; \
        *(s16x8*)(&lb[BUF][r][scol]) = rb[q]; } }

    LG_LOAD(0);
    LG_WRITE(0);
    __syncthreads();
    for (int ks = 0; ks < 16; ++ks) {
        const int cur = ks & 1;
        if (ks < 15) LG_LOAD((ks + 1) * 32);
        s16x8 af[4], bfr[4];
#pragma unroll
        for (int i = 0; i < 4; ++i) af[i]  = *(const s16x8*)(&la[cur][wr + i * 16 + frl][kb]);
#pragma unroll
        for (int i = 0; i < 4; ++i) bfr[i] = *(const s16x8*)(&lb[cur][wc + i * 16 + frl][kb]);
#pragma unroll
        for (int mi = 0; mi < 4; ++mi)
#pragma unroll
            for (int ni = 0; ni < 4; ++ni)
                acc[mi][ni] = __builtin_amdgcn_mfma_f32_16x16x32_bf16(af[mi], bfr[ni], acc[mi][ni], 0, 0, 0);
        if (ks < 15) LG_WRITE(cur ^ 1);
        __syncthreads();
    }
#undef LG_LOAD
#undef LG_WRITE

    // Epilogue: mask + store L + per-column (max, sumexp) over this tile's 128 rows.
    float cm[4], cz[4];
#pragma unroll
    for (int ni = 0; ni < 4; ++ni) {
        const int colg = s0 + wc + ni * 16 + frl;
        float xs[4][4];
        float ml = SENT;
#pragma unroll
        for (int mi = 0; mi < 4; ++mi)
#pragma unroll
            for (int r = 0; r < 4; ++r) {
                int row = t0 + wr + mi * 16 + rg4 + r;
                float x = (colg <= row) ? acc[mi][ni][r] : SENT;
                Lb[(size_t)row * 2048 + colg] = x;
                xs[mi][r] = x;
                ml = fmaxf(ml, x);
            }
        ml = fmaxf(ml, __shfl_xor(ml, 16));
        ml = fmaxf(ml, __shfl_xor(ml, 32));   // max over the 4 row-groups
        float zl = 0.f;
#pragma unroll
        for (int mi = 0; mi < 4; ++mi)
#pragma unroll
            for (int r = 0; r < 4; ++r)
                zl += __expf(xs[mi][r] - ml);
        zl += __shfl_xor(zl, 16);
        zl += __shfl_xor(zl, 32);
        cm[ni] = ml; cz[ni] = zl;
    }
    if (lane < 16) {
#pragma unroll
        for (int ni = 0; ni < 4; ++ni) {
            sm[wr >> 6][wc + ni * 16 + lane] = cm[ni];
            sz[wr >> 6][wc + ni * 16 + lane] = cz[ni];
        }
    }
    __syncthreads();
    if (tid < 128) {
        float M0 = sm[0][tid], M1 = sm[1][tid];
        float M = fmaxf(M0, M1);
        float Z = sz[0][tid] * __expf(M0 - M) + sz[1][tid] * __expf(M1 - M);
        int o = (b * 16 + tt) * 2048 + s0 + tid;
        pm[o] = M; pz[o] = Z;
    }
}

// Combine 16 chunk partials -> column max + rcp = 1/(Z*sqrt(512)).
// Chunks tc < s>>7 were never written (fully-masked region) -> skipped.
__global__ __launch_bounds__(256) void k_stats2(
    const float* __restrict__ pm, const float* __restrict__ pz,
    float* __restrict__ mcol, float* __restrict__ rcp)
{
    const int i = blockIdx.x * 256 + threadIdx.x;  // b*2048 + s
    const int b = i >> 11, s = i & 2047;
    const int tc0 = s >> 7;
    float M = SENT;
    for (int tc = tc0; tc < 16; ++tc) M = fmaxf(M, pm[(b * 16 + tc) * 2048 + s]);
    float Z = 0.f;
    for (int tc = tc0; tc < 16; ++tc) {
        int o = (b * 16 + tc) * 2048 + s;
        Z += pz[o] * __expf(pm[o] - M);
    }
    mcol[i] = M;
    rcp[i]  = 1.0f / (Z * SQRTK);
}

// ---------------------------------------------------------------------------
// out[b,t,v] = x[b,t,v] + sum_s exp(L[t,s]-m_s)*rcp_s * Vt[v, b*2048+s]
// Double-buffered (reg-staged loads, fused exp). 1-D grid with complementary
// t-tile pairing: block id and id+256 land on the same CU (round-robin over
// 256 CUs) and get t-tiles (tt, 15-tt) -> uniform 17 s-tiles per CU.
// ---------------------------------------------------------------------------
__global__ __launch_bounds__(256) void k_out(
    const float* __restrict__ L,           // [B][2048][2048]
    const float* __restrict__ mcol,        // [B*2048]
    const float* __restrict__ rcp,         // [B*2048]
    const unsigned short* __restrict__ Vt, // [512][B*2048] bf16
    const float* __restrict__ X,           // [B][2048][512] fp32
    float* __restrict__ Y)                 // [B][2048][512] fp32
{
    __shared__ short la[2][128][32];   // P'[t][s]
    __shared__ short lb[2][128][32];   // Vt[v][s]
    const int n  = blockIdx.x;
    const int lo = n & 255, hi = n >> 8;
    const int tt8 = lo & 7, v = (lo >> 3) & 3, b = lo >> 5;
    const int tt = hi ? (15 - tt8) : tt8;
    const int t0 = tt * 128, v0 = v * 128;
    const float* Lb = L + (size_t)b * 2048 * 2048;
    const float* mb = mcol + b * 2048;
    const float* rb = rcp  + b * 2048;
    const int tid  = threadIdx.x;
    const int wave = tid >> 6, lane = tid & 63;
    const int wr = (wave >> 1) * 64, wc = (wave & 1) * 64;
    const int frl = lane & 15, kb = (lane >> 4) * 8, rg4 = (lane >> 4) * 4;

    // staging coords
    const int sc  = (tid & 7) * 4;   // A col group (4 floats), same for all p
    const int tr0 = tid >> 3;        // A row base (0..31), +32 per p
    const int scB = (tid & 3) * 8;   // B col group (8 shorts)
    const int vr0 = tid >> 2;        // B row base (0..63), +64 per p

    f32x4 acc[4][4] = {};
    f32x4 lA[4], m4, r4;
    s16x8 vb0, vb1;
    const int nst = (tt + 1) * 4;    // 32-wide s-steps (causal)

#define OUT_LOAD(IS) \
    { int s0_ = (IS) * 32; \
      _Pragma("unroll") for (int p = 0; p < 4; ++p) \
          lA[p] = *(const f32x4*)(Lb + (size_t)(t0 + tr0 + p * 32) * 2048 + s0_ + sc); \
      m4 = *(const f32x4*)(mb + s0_ + sc); \
      r4 = *(const f32x4*)(rb + s0_ + sc); \
      vb0 = *(const s16x8*)(Vt + (size_t)(v0 + vr0) * 16384 + b * 2048 + s0_ + scB); \
      vb1 = *(const s16x8*)(Vt + (size_t)(v0 + vr0 + 64) * 16384 + b * 2048 + s0_ + scB); }
#define OUT_WRITE(BUF) \
    { _Pragma("unroll") for (int p = 0; p < 4; ++p) { \
          s16x4 o_; \
          _Pragma("unroll") for (int j = 0; j < 4; ++j) \
              o_[j] = f2bf(__expf(lA[p][j] - m4[j]) * r4[j]); \
          *(s16x4*)(&la[BUF][tr0 + p * 32][sc]) = o_; } \
      *(s16x8*)(&lb[BUF][vr0][scB]) = vb0; \
      *(s16x8*)(&lb[BUF][vr0 + 64][scB]) = vb1; }

    OUT_LOAD(0);
    OUT_WRITE(0);
    __syncthreads();
    for (int is = 0; is < nst; ++is) {
        const int cur = is & 1;
        if (is + 1 < nst) OUT_LOAD(is + 1);
        s16x8 af[4], bfr[4];
#pragma unroll
        for (int i = 0; i < 4; ++i) af[i]  = *(const s16x8*)(&la[cur][wr + i * 16 + frl][kb]);
#pragma unroll
        for (int i = 0; i < 4; ++i) bfr[i] = *(const s16x8*)(&lb[cur][wc + i * 16 + frl][kb]);
#pragma unroll
        for (int mi = 0; mi < 4; ++mi)
#pragma unroll
            for (int ni = 0; ni < 4; ++ni)
                acc[mi][ni] = __builtin_amdgcn_mfma_f32_16x16x32_bf16(af[mi], bfr[ni], acc[mi][ni], 0, 0, 0);
        if (is + 1 < nst) OUT_WRITE(cur ^ 1);
        __syncthreads();
    }
#undef OUT_LOAD
#undef OUT_WRITE

#pragma unroll
    for (int mi = 0; mi < 4; ++mi)
#pragma unroll
        for (int ni = 0; ni < 4; ++ni) {
            int col = v0 + wc + ni * 16 + frl;
#pragma unroll
            for (int r = 0; r < 4; ++r) {
                int row = t0 + wr + mi * 16 + rg4 + r;
                size_t o = ((size_t)b * 2048 + row) * 512 + col;
                Y[o] = acc[mi][ni][r] + X[o];
            }
        }
}

extern "C" void kernel_launch(void* const* d_in, const int* in_sizes, int n_in,
                              void* d_out, int out_size, void* d_ws, size_t ws_size,
                              hipStream_t stream) {
    const float* Xf  = (const float*)d_in[0];
    const float* Wkf = (const float*)d_in[1];
    const float* bkf = (const float*)d_in[2];
    const float* Wqf = (const float*)d_in[3];
    const float* bqf = (const float*)d_in[4];
    const float* Wvf = (const float*)d_in[5];
    const float* bvf = (const float*)d_in[6];
    float* Y = (float*)d_out;
    char* ws = (char*)d_ws;

    // workspace layout (bytes); total ~193.5 MB
    // Xb is dead after the projections; pm/pz/mc/rc overlay it (written by
    // k_logits/k_stats2 which run strictly after all k_proj).
    unsigned short* Xb  = (unsigned short*)(ws);                    // 16 MB  [16384][512]
    float*          pm  = (float*)(ws);                             // 1 MB   [8*16][2048] (overlays Xb)
    float*          pz  = (float*)(ws + 1048576);                   // 1 MB
    float*          mc  = (float*)(ws + 2097152);                   // 64 KB
    float*          rc  = (float*)(ws + 2162688);                   // 64 KB
    unsigned short* Qb  = (unsigned short*)(ws + 16777216);         // 16 MB  [16384][512]
    unsigned short* Kb  = (unsigned short*)(ws + 33554432);         // 16 MB  [16384][512]
    unsigned short* Vt  = (unsigned short*)(ws + 50331648);         // 16 MB  [512][16384]
    unsigned short* Wkb = (unsigned short*)(ws + 67108864);         // 512 KB [512][512]
    unsigned short* Wqb = (unsigned short*)(ws + 67633152);         // 512 KB
    unsigned short* Wvb = (unsigned short*)(ws + 68157440);         // 512 KB
    float*          Lg  = (float*)(ws + 68681728);                  // 128 MB [8][2048][2048]

    dim3 blk(256);
    // fp32 -> bf16 casts
    k_cast<<<dim3(8192), blk, 0, stream>>>(Xf, Xb, 2097152);
    k_castw<<<dim3(768), blk, 0, stream>>>(Wkf, Wqf, Wvf, Wkb, Wqb, Wvb);
    // Q = X.Wq^T + bq ; K = X.Wk^T + bk  (M=16384, N=512)
    k_proj<<<dim3(128, 4), blk, 0, stream>>>(Xb, Wqb, bqf, Qb, 512, 0);
    k_proj<<<dim3(128, 4), blk, 0, stream>>>(Xb, Wkb, bkf, Kb, 512, 0);
    // Vt = Wv.X^T + bv (per-row bias) -> values transposed [512][16384]
    k_proj<<<dim3(4, 128), blk, 0, stream>>>(Wvb, Xb, bvf, Vt, 16384, 1);
    // logits + fused column-stats partials (1088 uniform triangular blocks)
    k_logits<<<dim3(1088), blk, 0, stream>>>(Qb, Kb, Lg, pm, pz);
    // combine partials -> per-column max + 1/(Z*sqrt(512))
    k_stats2<<<dim3(64), blk, 0, stream>>>(pm, pz, mc, rc);
    // P.V + residual (complementary-pair balanced, double-buffered)
    k_out<<<dim3(512), blk, 0, stream>>>(Lg, mc, rc, Vt, Xf, Y);
}